// Round 1
// baseline (657.393 us; speedup 1.0000x reference)
//
#include <hip/hip_runtime.h>
#include <math.h>

// Problem constants (from reference)
#define BB   64
#define NN   16384
#define MM   64
#define CIN  512
#define OUTD 198          // 3*M + 6
#define EPSF 1e-8f

#define NCHUNK (NN / 256)        // 64 chunks of 256 n-values per batch
#define NBLK   (BB * NCHUNK)     // 4096 blocks for the big passes

__device__ inline float softplusf(float v) {
    // matches jax.nn.softplus = log1p(exp(x)) with overflow guard
    return v > 20.f ? v : log1pf(expf(v));
}
__device__ inline float sigmoidf(float v) {
    return 1.f / (1.f + expf(-v));
}

// ---------------------------------------------------------------------------
// Kernel A: proj = x @ W + b  (64 x 198 x 512, trivial) + per-b scalars
// scal[b*8 + {0..6}] = beta, g, s0, s1, s2, gamma, knorm
// ---------------------------------------------------------------------------
__global__ __launch_bounds__(256) void proj_kernel(
    const float* __restrict__ x, const float* __restrict__ W,
    const float* __restrict__ bias, float* __restrict__ out_proj,
    float* __restrict__ scal)
{
    const int b = blockIdx.x;
    const int tid = threadIdx.x;
    __shared__ __align__(16) float xs[CIN];
    __shared__ float pr[OUTD];

    for (int c = tid; c < CIN; c += 256) xs[c] = x[b * CIN + c];
    __syncthreads();

    if (tid < OUTD) {
        float acc = bias[tid];
        #pragma unroll 8
        for (int c = 0; c < CIN; ++c)
            acc = fmaf(xs[c], W[c * OUTD + tid], acc);
        out_proj[b * OUTD + tid] = acc;
        pr[tid] = acc;
    }
    __syncthreads();

    if (tid == 0) {
        float beta  = softplusf(pr[MM]);
        float g     = sigmoidf(pr[MM + 1]);
        float s0r = pr[MM + 2], s1r = pr[MM + 3], s2r = pr[MM + 4];
        float mx  = fmaxf(s0r, fmaxf(s1r, s2r));
        float e0 = expf(s0r - mx), e1 = expf(s1r - mx), e2 = expf(s2r - mx);
        float inv = 1.f / (e0 + e1 + e2);
        float gamma = 1.f + softplusf(pr[MM + 5]);
        float ksq = 0.f;
        for (int m = 0; m < MM; ++m) ksq += pr[m] * pr[m];
        float* sc = scal + b * 8;
        sc[0] = beta; sc[1] = g;
        sc[2] = e0 * inv; sc[3] = e1 * inv; sc[4] = e2 * inv;
        sc[5] = gamma; sc[6] = sqrtf(ksq);
    }
}

// ---------------------------------------------------------------------------
// Kernel B: score[b,n] = beta * dot(mem[b,n,:],k) / (||mem[b,n,:]||*||k||+eps)
// + per-block online-softmax partials (max, sum-exp)
// ---------------------------------------------------------------------------
__global__ __launch_bounds__(256) void score_kernel(
    const float* __restrict__ mem, const float* __restrict__ proj,
    const float* __restrict__ scal, float* __restrict__ score,
    float* __restrict__ partials)
{
    const int b     = blockIdx.x >> 6;
    const int chunk = blockIdx.x & 63;
    const int tid   = threadIdx.x;
    const int n     = chunk * 256 + tid;

    __shared__ __align__(16) float ks[MM];
    __shared__ float red[8];

    if (tid < MM) ks[tid] = proj[b * OUTD + tid];   // k = proj[:, :M]
    __syncthreads();

    const float4* row = (const float4*)(mem + ((size_t)b * NN + n) * MM);
    float dot = 0.f, nsq = 0.f;
    #pragma unroll
    for (int i = 0; i < MM / 4; ++i) {
        float4 v  = row[i];
        float4 kv = *(const float4*)(&ks[i * 4]);
        dot += v.x * kv.x + v.y * kv.y + v.z * kv.z + v.w * kv.w;
        nsq += v.x * v.x + v.y * v.y + v.z * v.z + v.w * v.w;
    }
    const float beta  = scal[b * 8 + 0];
    const float knorm = scal[b * 8 + 6];
    const float sc = beta * dot / (sqrtf(nsq) * knorm + EPSF);
    score[(size_t)b * NN + n] = sc;

    // block max
    float mv = sc;
    #pragma unroll
    for (int o = 32; o > 0; o >>= 1) mv = fmaxf(mv, __shfl_xor(mv, o));
    const int wid = tid >> 6, lane = tid & 63;
    if (lane == 0) red[wid] = mv;
    __syncthreads();
    if (tid == 0) red[4] = fmaxf(fmaxf(red[0], red[1]), fmaxf(red[2], red[3]));
    __syncthreads();
    const float mb = red[4];

    // block sum of exp(sc - mb)
    float ex = expf(sc - mb);
    #pragma unroll
    for (int o = 32; o > 0; o >>= 1) ex += __shfl_xor(ex, o);
    if (lane == 0) red[wid] = ex;
    __syncthreads();
    if (tid == 0) {
        partials[2 * blockIdx.x]     = mb;
        partials[2 * blockIdx.x + 1] = red[0] + red[1] + red[2] + red[3];
    }
}

// ---------------------------------------------------------------------------
// Kernel C: merge per-block (max, sumexp) -> per-b (M, S); zero sumW
// one wave per batch (64 partials per b)
// ---------------------------------------------------------------------------
__global__ __launch_bounds__(64) void combine_kernel(
    const float* __restrict__ partials, float* __restrict__ Mb,
    float* __restrict__ Sb, float* __restrict__ sumW)
{
    const int b = blockIdx.x, t = threadIdx.x;
    const float mb = partials[2 * (b * NCHUNK + t)];
    const float sb = partials[2 * (b * NCHUNK + t) + 1];
    float M = mb;
    #pragma unroll
    for (int o = 32; o > 0; o >>= 1) M = fmaxf(M, __shfl_xor(M, o));
    float contrib = sb * expf(mb - M);
    #pragma unroll
    for (int o = 32; o > 0; o >>= 1) contrib += __shfl_xor(contrib, o);
    if (t == 0) { Mb[b] = M; Sb[b] = contrib; sumW[b] = 0.f; }
}

// ---------------------------------------------------------------------------
// Kernel F: w_c -> w_g -> shifted w_s -> w_sharp = (w_s+eps)^gamma
// circular +-1 halo staged in LDS; per-b sum via atomicAdd
// ---------------------------------------------------------------------------
__global__ __launch_bounds__(256) void sharp_kernel(
    const float* __restrict__ score, const float* __restrict__ w_prev,
    const float* __restrict__ scal, const float* __restrict__ Mb,
    const float* __restrict__ Sb, float* __restrict__ wsharp,
    float* __restrict__ sumW)
{
    const int b     = blockIdx.x >> 6;
    const int chunk = blockIdx.x & 63;
    const int tid   = threadIdx.x;
    const int start = chunk * 256;

    __shared__ float wg[258];
    __shared__ float red[8];

    const float g    = scal[b * 8 + 1];
    const float Mv   = Mb[b];
    const float invS = 1.f / Sb[b];
    const float* scb = score  + (size_t)b * NN;
    const float* wpb = w_prev + (size_t)b * NN;

    for (int i = tid; i < 258; i += 256) {
        const int idx = (start - 1 + i + NN) & (NN - 1);
        const float wc = expf(scb[idx] - Mv) * invS;
        wg[i] = g * wc + (1.f - g) * wpb[idx];
    }
    __syncthreads();

    const float s0 = scal[b * 8 + 2], s1 = scal[b * 8 + 3];
    const float s2 = scal[b * 8 + 4], gamma = scal[b * 8 + 5];
    // roll(wg,-1)[n]=wg[n+1]; roll(wg,+1)[n]=wg[n-1]; wg[i] holds n=start-1+i
    const float ws  = s0 * wg[tid + 2] + s1 * wg[tid + 1] + s2 * wg[tid];
    const float wsh = powf(ws + EPSF, gamma);
    wsharp[(size_t)b * NN + start + tid] = wsh;

    float sum = wsh;
    #pragma unroll
    for (int o = 32; o > 0; o >>= 1) sum += __shfl_xor(sum, o);
    const int wid = tid >> 6, lane = tid & 63;
    if (lane == 0) red[wid] = sum;
    __syncthreads();
    if (tid == 0) atomicAdd(&sumW[b], red[0] + red[1] + red[2] + red[3]);
}

// ---------------------------------------------------------------------------
// Kernel H: w = wsharp / sumW (written to out) ;
//           mem_new = memory*(1 - w*e) + w*a
// block order reversed: tail of `memory` is still L3-resident from kernel B
// ---------------------------------------------------------------------------
__global__ __launch_bounds__(256) void update_kernel(
    const float* __restrict__ mem, const float* __restrict__ proj,
    const float* __restrict__ wsharp, const float* __restrict__ sumW,
    float* __restrict__ out_w, float* __restrict__ out_mem)
{
    const int blk   = (int)gridDim.x - 1 - (int)blockIdx.x;
    const int b     = blk >> 6;
    const int chunk = blk & 63;
    const int tid   = threadIdx.x;
    const int n     = chunk * 256 + tid;

    __shared__ __align__(16) float es[MM];
    __shared__ __align__(16) float as_[MM];
    if (tid < MM) {
        es[tid]  = sigmoidf(proj[b * OUTD + MM + 6 + tid]);   // e = sigmoid
        as_[tid] = proj[b * OUTD + MM + 6 + MM + tid];        // a = raw
    }
    __syncthreads();

    const float w = wsharp[(size_t)b * NN + n] / sumW[b];
    out_w[(size_t)b * NN + n] = w;

    const float4* row  = (const float4*)(mem     + ((size_t)b * NN + n) * MM);
    float4*       orow = (float4*)      (out_mem + ((size_t)b * NN + n) * MM);
    #pragma unroll
    for (int i = 0; i < MM / 4; ++i) {
        const float4 v  = row[i];
        const float4 e4 = *(const float4*)(&es[i * 4]);
        const float4 a4 = *(const float4*)(&as_[i * 4]);
        float4 r;
        r.x = v.x * (1.f - w * e4.x) + w * a4.x;
        r.y = v.y * (1.f - w * e4.y) + w * a4.y;
        r.z = v.z * (1.f - w * e4.z) + w * a4.z;
        r.w = v.w * (1.f - w * e4.w) + w * a4.w;
        orow[i] = r;
    }
}

// ---------------------------------------------------------------------------
extern "C" void kernel_launch(void* const* d_in, const int* in_sizes, int n_in,
                              void* d_out, int out_size, void* d_ws, size_t ws_size,
                              hipStream_t stream)
{
    const float* x      = (const float*)d_in[0];
    const float* w_prev = (const float*)d_in[1];
    const float* memory = (const float*)d_in[2];
    const float* W      = (const float*)d_in[3];
    const float* bias   = (const float*)d_in[4];

    float* out      = (float*)d_out;
    float* out_proj = out;                              // B*OUT
    float* out_w    = out + BB * OUTD;                  // B*N
    float* out_mem  = out_w + (size_t)BB * NN;          // B*N*M

    // workspace layout (floats)
    float* ws_f     = (float*)d_ws;
    float* score    = ws_f;                             // B*N
    float* wsharp   = score + (size_t)BB * NN;          // B*N
    float* partials = wsharp + (size_t)BB * NN;         // 2*NBLK
    float* Mb       = partials + 2 * NBLK;              // B
    float* Sb       = Mb + BB;                          // B
    float* sumW     = Sb + BB;                          // B
    float* scal     = sumW + BB;                        // 8*B

    proj_kernel   <<<BB,   256, 0, stream>>>(x, W, bias, out_proj, scal);
    score_kernel  <<<NBLK, 256, 0, stream>>>(memory, out_proj, scal, score, partials);
    combine_kernel<<<BB,    64, 0, stream>>>(partials, Mb, Sb, sumW);
    sharp_kernel  <<<NBLK, 256, 0, stream>>>(score, w_prev, scal, Mb, Sb, wsharp, sumW);
    update_kernel <<<NBLK, 256, 0, stream>>>(memory, out_proj, wsharp, sumW, out_w, out_mem);
}

// Round 3
// 572.813 us; speedup vs baseline: 1.1477x; 1.1477x over previous
//
#include <hip/hip_runtime.h>
#include <math.h>

// Problem constants (from reference)
#define BB   64
#define NN   16384
#define MM   64
#define CIN  512
#define OUTD 198          // 3*M + 6
#define EPSF 1e-8f

#define NCHUNK (NN / 256)        // 64 chunks of 256 n-values per batch
#define NBLK   (BB * NCHUNK)     // 4096 blocks for score/sharp passes
#define UPD_BLKS 16384           // update: 4096 floats per block

__device__ inline float softplusf(float v) {
    return v > 20.f ? v : log1pf(expf(v));
}
__device__ inline float sigmoidf(float v) {
    return 1.f / (1.f + expf(-v));
}

// ---------------------------------------------------------------------------
// Kernel A: proj = x @ W + b  (64 x 198 x 512) + per-b scalars + e/a table
// scal[b*8 + {0..6}] = beta, g, s0, s1, s2, gamma, knorm
// ea[b*128 + m] = sigmoid(proj[M+6+m]) ; ea[b*128 + 64 + m] = proj[M+6+M+m]
// ---------------------------------------------------------------------------
__global__ __launch_bounds__(256) void proj_kernel(
    const float* __restrict__ x, const float* __restrict__ W,
    const float* __restrict__ bias, float* __restrict__ out_proj,
    float* __restrict__ scal, float* __restrict__ ea)
{
    const int b = blockIdx.x;
    const int tid = threadIdx.x;
    __shared__ __align__(16) float xs[CIN];
    __shared__ float pr[OUTD];

    for (int c = tid; c < CIN; c += 256) xs[c] = x[b * CIN + c];
    __syncthreads();

    if (tid < OUTD) {
        float acc = bias[tid];
        #pragma unroll 8
        for (int c = 0; c < CIN; ++c)
            acc = fmaf(xs[c], W[c * OUTD + tid], acc);
        out_proj[b * OUTD + tid] = acc;
        pr[tid] = acc;
    }
    __syncthreads();

    if (tid < MM) {
        ea[b * 128 + tid]      = sigmoidf(pr[MM + 6 + tid]);  // e
        ea[b * 128 + 64 + tid] = pr[MM + 6 + MM + tid];       // a
    }
    if (tid == 0) {
        float beta  = softplusf(pr[MM]);
        float g     = sigmoidf(pr[MM + 1]);
        float s0r = pr[MM + 2], s1r = pr[MM + 3], s2r = pr[MM + 4];
        float mx  = fmaxf(s0r, fmaxf(s1r, s2r));
        float e0 = expf(s0r - mx), e1 = expf(s1r - mx), e2 = expf(s2r - mx);
        float inv = 1.f / (e0 + e1 + e2);
        float gamma = 1.f + softplusf(pr[MM + 5]);
        float ksq = 0.f;
        for (int m = 0; m < MM; ++m) ksq += pr[m] * pr[m];
        float* sc = scal + b * 8;
        sc[0] = beta; sc[1] = g;
        sc[2] = e0 * inv; sc[3] = e1 * inv; sc[4] = e2 * inv;
        sc[5] = gamma; sc[6] = sqrtf(ksq);
    }
}

// ---------------------------------------------------------------------------
// Kernel B: score[b,n] = beta * dot(mem[b,n,:],k) / (||mem[b,n,:]||*||k||+eps)
// COALESCED: 16 lanes per row x float4; shfl-xor reduce within 16-lane group.
// Each block: 256 rows via 16 iterations of 16 rows (4 KB contiguous / iter).
// ---------------------------------------------------------------------------
__global__ __launch_bounds__(256) void score_kernel(
    const float* __restrict__ mem, const float* __restrict__ proj,
    const float* __restrict__ scal, float* __restrict__ score,
    float* __restrict__ partials)
{
    const int b     = blockIdx.x >> 6;
    const int chunk = blockIdx.x & 63;
    const int tid   = threadIdx.x;
    const int rowbase = chunk * 256;

    __shared__ __align__(16) float ks[MM];
    __shared__ float rowsc[256];
    __shared__ float red[8];

    if (tid < MM) ks[tid] = proj[b * OUTD + tid];   // k = proj[:, :M]
    __syncthreads();

    const float beta  = scal[b * 8 + 0];
    const float knorm = scal[b * 8 + 6];
    const int sub = tid & 15;        // lane within row (float4 index)
    const int rg  = tid >> 4;        // row group 0..15
    const float4 kv = *(const float4*)(&ks[sub * 4]);
    const float4* base = (const float4*)(mem + ((size_t)b * NN + rowbase) * MM);

    #pragma unroll
    for (int it = 0; it < 16; ++it) {
        const float4 v = base[(it * 16 + rg) * 16 + sub];
        float dot = v.x * kv.x + v.y * kv.y + v.z * kv.z + v.w * kv.w;
        float nsq = v.x * v.x + v.y * v.y + v.z * v.z + v.w * v.w;
        #pragma unroll
        for (int o = 1; o < 16; o <<= 1) {
            dot += __shfl_xor(dot, o);
            nsq += __shfl_xor(nsq, o);
        }
        if (sub == 0) {
            const float sc = beta * dot / (sqrtf(nsq) * knorm + EPSF);
            score[(size_t)b * NN + rowbase + it * 16 + rg] = sc;
            rowsc[it * 16 + rg] = sc;
        }
    }
    __syncthreads();

    // block softmax partials over the 256 row scores
    const float sc = rowsc[tid];
    float mv = sc;
    #pragma unroll
    for (int o = 32; o > 0; o >>= 1) mv = fmaxf(mv, __shfl_xor(mv, o));
    const int wid = tid >> 6, lane = tid & 63;
    if (lane == 0) red[wid] = mv;
    __syncthreads();
    if (tid == 0) red[4] = fmaxf(fmaxf(red[0], red[1]), fmaxf(red[2], red[3]));
    __syncthreads();
    const float mb = red[4];

    float ex = expf(sc - mb);
    #pragma unroll
    for (int o = 32; o > 0; o >>= 1) ex += __shfl_xor(ex, o);
    if (lane == 0) red[wid] = ex;
    __syncthreads();
    if (tid == 0) {
        partials[2 * blockIdx.x]     = mb;
        partials[2 * blockIdx.x + 1] = red[0] + red[1] + red[2] + red[3];
    }
}

// ---------------------------------------------------------------------------
// Kernel C: merge per-block (max, sumexp) -> per-b (M, S); zero sumW
// ---------------------------------------------------------------------------
__global__ __launch_bounds__(64) void combine_kernel(
    const float* __restrict__ partials, float* __restrict__ Mb,
    float* __restrict__ Sb, float* __restrict__ sumW)
{
    const int b = blockIdx.x, t = threadIdx.x;
    const float mb = partials[2 * (b * NCHUNK + t)];
    const float sb = partials[2 * (b * NCHUNK + t) + 1];
    float M = mb;
    #pragma unroll
    for (int o = 32; o > 0; o >>= 1) M = fmaxf(M, __shfl_xor(M, o));
    float contrib = sb * expf(mb - M);
    #pragma unroll
    for (int o = 32; o > 0; o >>= 1) contrib += __shfl_xor(contrib, o);
    if (t == 0) { Mb[b] = M; Sb[b] = contrib; sumW[b] = 0.f; }
}

// ---------------------------------------------------------------------------
// Kernel F: w_c -> w_g -> shifted w_s -> w_sharp = (w_s+eps)^gamma
// ---------------------------------------------------------------------------
__global__ __launch_bounds__(256) void sharp_kernel(
    const float* __restrict__ score, const float* __restrict__ w_prev,
    const float* __restrict__ scal, const float* __restrict__ Mb,
    const float* __restrict__ Sb, float* __restrict__ wsharp,
    float* __restrict__ sumW)
{
    const int b     = blockIdx.x >> 6;
    const int chunk = blockIdx.x & 63;
    const int tid   = threadIdx.x;
    const int start = chunk * 256;

    __shared__ float wg[258];
    __shared__ float red[8];

    const float g    = scal[b * 8 + 1];
    const float Mv   = Mb[b];
    const float invS = 1.f / Sb[b];
    const float* scb = score  + (size_t)b * NN;
    const float* wpb = w_prev + (size_t)b * NN;

    for (int i = tid; i < 258; i += 256) {
        const int idx = (start - 1 + i + NN) & (NN - 1);
        const float wc = expf(scb[idx] - Mv) * invS;
        wg[i] = g * wc + (1.f - g) * wpb[idx];
    }
    __syncthreads();

    const float s0 = scal[b * 8 + 2], s1 = scal[b * 8 + 3];
    const float s2 = scal[b * 8 + 4], gamma = scal[b * 8 + 5];
    const float ws  = s0 * wg[tid + 2] + s1 * wg[tid + 1] + s2 * wg[tid];
    const float wsh = powf(ws + EPSF, gamma);
    wsharp[(size_t)b * NN + start + tid] = wsh;

    float sum = wsh;
    #pragma unroll
    for (int o = 32; o > 0; o >>= 1) sum += __shfl_xor(sum, o);
    const int wid = tid >> 6, lane = tid & 63;
    if (lane == 0) red[wid] = sum;
    __syncthreads();
    if (tid == 0) atomicAdd(&sumW[b], red[0] + red[1] + red[2] + red[3]);
}

// ---------------------------------------------------------------------------
// Kernel H: w = wsharp/sumW -> out_w ; mem_new = memory*(1-w*e) + w*a
// COALESCED: flat float4 over b*N*M. 16 lanes share one n (broadcast w).
// Block = 4096 floats (64 rows) of one batch; 4 iterations of 1024 floats.
// Block order reversed so the tail of `memory` (still L3-resident from the
// score pass) is read first.
// ---------------------------------------------------------------------------
__global__ __launch_bounds__(256) void update_kernel(
    const float* __restrict__ mem, const float* __restrict__ ea_g,
    const float* __restrict__ wsharp, const float* __restrict__ sumW,
    float* __restrict__ out_w, float* __restrict__ out_mem)
{
    const int blk = UPD_BLKS - 1 - (int)blockIdx.x;   // reversed
    const int tid = threadIdx.x;
    const int b   = blk >> 8;                         // 256 blocks per batch

    __shared__ __align__(16) float ea[128];
    if (tid < 32) *(float4*)(&ea[tid * 4]) =
        *(const float4*)(&ea_g[b * 128 + tid * 4]);
    __syncthreads();

    const int m = (tid * 4) & 63;
    const float4 e4 = *(const float4*)(&ea[m]);
    const float4 a4 = *(const float4*)(&ea[64 + m]);
    const float invS = 1.0f / sumW[b];
    const size_t base_f = (size_t)blk * 4096;
    const float* wsb = wsharp + (size_t)b * NN;
    float*       owb = out_w  + (size_t)b * NN;

    #pragma unroll
    for (int it = 0; it < 4; ++it) {
        const size_t off = base_f + (size_t)it * 1024 + tid * 4;
        const int n = (int)((off >> 6) & (NN - 1));
        const float w = wsb[n] * invS;
        if ((tid & 15) == 0) owb[n] = w;
        const float4 v = *(const float4*)(mem + off);
        float4 r;
        r.x = v.x * (1.f - w * e4.x) + w * a4.x;
        r.y = v.y * (1.f - w * e4.y) + w * a4.y;
        r.z = v.z * (1.f - w * e4.z) + w * a4.z;
        r.w = v.w * (1.f - w * e4.w) + w * a4.w;
        *(float4*)(out_mem + off) = r;
    }
}

// ---------------------------------------------------------------------------
extern "C" void kernel_launch(void* const* d_in, const int* in_sizes, int n_in,
                              void* d_out, int out_size, void* d_ws, size_t ws_size,
                              hipStream_t stream)
{
    const float* x      = (const float*)d_in[0];
    const float* w_prev = (const float*)d_in[1];
    const float* memory = (const float*)d_in[2];
    const float* W      = (const float*)d_in[3];
    const float* bias   = (const float*)d_in[4];

    float* out      = (float*)d_out;
    float* out_proj = out;                              // B*OUT
    float* out_w    = out + BB * OUTD;                  // B*N
    float* out_mem  = out_w + (size_t)BB * NN;          // B*N*M

    // workspace layout (floats)
    float* ws_f     = (float*)d_ws;
    float* score    = ws_f;                             // B*N
    float* wsharp   = score + (size_t)BB * NN;          // B*N
    float* partials = wsharp + (size_t)BB * NN;         // 2*NBLK
    float* Mb       = partials + 2 * NBLK;              // B
    float* Sb       = Mb + BB;                          // B
    float* sumW     = Sb + BB;                          // B
    float* scal     = sumW + BB;                        // 8*B
    float* ea       = scal + 8 * BB;                    // 128*B

    proj_kernel   <<<BB,      256, 0, stream>>>(x, W, bias, out_proj, scal, ea);
    score_kernel  <<<NBLK,    256, 0, stream>>>(memory, out_proj, scal, score, partials);
    combine_kernel<<<BB,       64, 0, stream>>>(partials, Mb, Sb, sumW);
    sharp_kernel  <<<NBLK,    256, 0, stream>>>(score, w_prev, scal, Mb, Sb, wsharp, sumW);
    update_kernel <<<UPD_BLKS,256, 0, stream>>>(memory, ea, wsharp, sumW, out_w, out_mem);
}